// Round 7
// baseline (2795.123 us; speedup 1.0000x reference)
//
#include <hip/hip_runtime.h>
#include <hip/hip_bf16.h>
#include <stdint.h>

#define N_NODES 25600
#define N_EDGES 51200
#define NG      512

typedef __attribute__((ext_vector_type(4))) float f32x4;
typedef __attribute__((ext_vector_type(2))) float f32x2;
typedef __attribute__((ext_vector_type(8))) short bf16x8;

__device__ __forceinline__ float lrelu(float v){ return v > 0.f ? v : 0.01f*v; }
__device__ __forceinline__ float sigm(float v){ return 1.f/(1.f+__expf(-v)); }
__device__ __forceinline__ unsigned short f2b(float v){
  union { float f; uint32_t u; } x; x.f = v;
  uint32_t u = x.u;
  return (unsigned short)((u + 0x7FFFu + ((u>>16)&1u)) >> 16);
}
__device__ __forceinline__ float rl(float v, int l){
  return __int_as_float(__builtin_amdgcn_readlane(__float_as_int(v), l));
}

// ---------------- prep ----------------
// W2n[(k*64+o)*64 + d] = bf16(net2_w[(d*64+o)*128 + k])   (8192 x 64)
// gw6[(d*64+t)*8 + j]  : j=0..2 gru_wih rows (r,z,n) col d; 3..5 gru_whh; 6,7 pad
__global__ void k_prep(const float* __restrict__ net2_w, unsigned short* __restrict__ W2n,
                       const float* __restrict__ gwih, const float* __restrict__ gwhh,
                       float* __restrict__ gw6,
                       const float* __restrict__ lwih, const float* __restrict__ lwhh,
                       float* __restrict__ lwihT, float* __restrict__ lwhhT,
                       const float* __restrict__ lin1w, float* __restrict__ l1T,
                       const float* __restrict__ lin2w, float* __restrict__ l2T,
                       const float* __restrict__ lin0w, float* __restrict__ l0T) {
  const int total = 524288+32768+32768+16384+32768+53760+1536;
  for (int i = blockIdx.x*blockDim.x + threadIdx.x; i < total; i += gridDim.x*blockDim.x) {
    int idx = i;
    if (idx < 524288) {
      int n = idx >> 6, d = idx & 63;
      int k = n >> 6, o = n & 63;
      W2n[idx] = f2b(net2_w[(d*64+o)*128 + k]);
      continue;
    }
    idx -= 524288;
    if (idx < 32768) {
      int dt = idx >> 3, j = idx & 7;
      int d = dt >> 6, t = dt & 63;
      float v = 0.f;
      if (j < 3) v = gwih[(j*64+t)*64 + d];
      else if (j < 6) v = gwhh[((j-3)*64+t)*64 + d];
      gw6[idx] = v; continue;
    }
    idx -= 32768;
    if (idx < 32768) { int c = idx/256, j = idx%256; lwihT[idx] = lwih[j*128+c]; continue; }
    idx -= 32768;
    if (idx < 16384) { int d = idx/256, j = idx%256; lwhhT[idx] = lwhh[j*64+d]; continue; }
    idx -= 16384;
    if (idx < 32768) { int d = idx/512, j = idx%512; l1T[idx] = lin1w[j*64+d]; continue; }
    idx -= 32768;
    if (idx < 53760) { int j = idx/105, o = idx%105; l2T[idx] = lin2w[o*512+j]; continue; }
    idx -= 53760;
    { int f = idx/64, o = idx%64; l0T[idx] = lin0w[o*24+f]; }
  }
}

// ---------------- lin0: out = lrelu(x @ lin0_w.T + b); Q0 = out @ b2mat ----------------
__global__ __launch_bounds__(256) void k_lin0(const float* __restrict__ x, const float* __restrict__ l0T,
     const float* __restrict__ b, const float* __restrict__ net2_b,
     float* __restrict__ outf, float* __restrict__ Q) {
  int t = threadIdx.x & 63;
  int n = blockIdx.x*4 + (threadIdx.x>>6);
  float xv = (t < 24) ? x[n*24+t] : 0.f;
  float acc = b[t];
  #pragma unroll
  for (int f = 0; f < 24; ++f) acc += __shfl(xv, f) * l0T[f*64+t];
  acc = lrelu(acc);
  outf[n*64+t] = acc;
  float qa = 0.f;
  #pragma unroll 8
  for (int d = 0; d < 64; ++d) qa += __shfl(acc, d) * net2_b[d*64+t];
  Q[n*64+t] = qa;
}

// ---------------- ehT[k][e] = lrelu(edge_attr @ net1_w.T + b) ----------------
__global__ __launch_bounds__(256) void k_eh(const float* __restrict__ ea, const float* __restrict__ w,
    const float* __restrict__ b, float* __restrict__ ehT) {
  __shared__ float tile[128][65];
  int e0 = blockIdx.x*64;
  int tid = threadIdx.x;
  #pragma unroll
  for (int r = 0; r < 32; ++r) {
    int idx = tid + r*256; int el = idx >> 7, k = idx & 127;
    float4 a = *(const float4*)(ea + (size_t)(e0+el)*4);
    float4 ww = *(const float4*)(w + k*4);
    tile[k][el] = lrelu(a.x*ww.x + a.y*ww.y + a.z*ww.z + a.w*ww.w + b[k]);
  }
  __syncthreads();
  #pragma unroll
  for (int r = 0; r < 32; ++r) {
    int idx = tid + r*256; int k = idx >> 6, el = idx & 63;
    ehT[(size_t)k*N_EDGES + e0 + el] = tile[k][el];
  }
}

// ---------------- deterministic per-graph CSR by dst ----------------
__global__ __launch_bounds__(128) void k_csr(const int* __restrict__ ei, int* __restrict__ deg,
                                             int* __restrict__ off, int* __restrict__ csr) {
  __shared__ int cnt[50];
  __shared__ int cur[50];
  __shared__ int dloc[100];
  int g = blockIdx.x, t = threadIdx.x;
  const int* dst = ei + N_EDGES;
  if (t < 50) cnt[t] = 0;
  __syncthreads();
  if (t < 100) { dloc[t] = dst[g*100+t] - g*50; atomicAdd(&cnt[dloc[t]], 1); }
  __syncthreads();
  if (t == 0) { int run = 0; for (int i = 0; i < 50; ++i) { cur[i] = run; run += cnt[i]; } }
  __syncthreads();
  if (t < 50) { deg[g*50+t] = cnt[t]; off[g*50+t] = g*100 + cur[t]; }
  __syncthreads();
  if (t < 100) {
    int p = 0, me = dloc[t];
    for (int i = 0; i < t; ++i) p += (dloc[i] == me);   // deterministic rank
    csr[g*100 + cur[me] + p] = g*100 + t;
  }
}

// ---------------- per-step: T-form bilinear conv + GRU, 1 graph/block ----------------
// T[s][n=(k_lo,o)] = sum_d W2n[n,d]*x_bf16[s,d] (MFMA, f32 result in LDS)
// fin[v,o] = sum_{e->v} ( eh[e,2c]*T[src][o] + eh[e,2c+1]*T[src][64+o] )  (+ Q[src,o])
// then GRU update (round-4 k_upd math), h -> outf, Q' -> Qb.
__global__ __launch_bounds__(512, 4) void k_step(
    float* __restrict__ outf, const float* __restrict__ ehT,
    const unsigned short* __restrict__ W2n, float* __restrict__ Qb,
    const int* __restrict__ ei, const int* __restrict__ csr,
    const int* __restrict__ offs, const int* __restrict__ deg,
    const float* __restrict__ rootw, const float* __restrict__ conv_b,
    const float* __restrict__ gw6, const float* __restrict__ bih, const float* __restrict__ bhh,
    const float* __restrict__ net2_b) {
  __shared__ __align__(16) char  BtB[128*144];   // W2 chunk bf16 [n_loc][d], slot16 ^= (row&7)
  __shared__ __align__(16) float Tt[64*132];     // T f32 [s][128 + pad4], straight addressing
  __shared__ __align__(16) char  XbB[64*144];    // x bf16 [s][72 shorts]
  __shared__ float ehl[2][256];
  __shared__ int sel[100];
  __shared__ int offl[64];
  __shared__ int degl[64];
  __shared__ float invd[64];
  float* aggL = (float*)BtB;                     // overlay after chunk loop: [64][66]

  const int tid = threadIdx.x;
  const int g = blockIdx.x;
  const int wave = tid >> 6, lane = tid & 63;
  const int t = lane;
  const int q = lane >> 4, cc = lane & 15;
  const int mw = wave >> 1, nh = wave & 1;

  // ---- stage meta + x ----
  if (tid < 64) {
    int dgv = 0, ofv = 0;
    if (tid < 50) { dgv = deg[g*50+tid]; ofv = offs[g*50+tid] - g*100; }
    degl[tid] = dgv; offl[tid] = ofv;
    invd[tid] = 1.f/(float)(dgv > 0 ? dgv : 1);
  }
  if (tid < 100) {
    int eg = csr[g*100+tid];
    sel[tid] = (ei[eg]-g*50) | ((eg-g*100) << 16);
  }
  for (int i = tid; i < 64*72; i += 512) ((unsigned short*)XbB)[i] = 0;
  __syncthreads();
  for (int i = tid; i < 3200; i += 512) {
    int n = i >> 6, d = i & 63;
    ((unsigned short*)XbB)[n*72+d] = f2b(outf[(size_t)g*3200 + i]);
  }
  __syncthreads();

  // X fragments in registers (chunk-invariant): xf[b][ks], b = s-half, ks = d-half
  bf16x8 xf00, xf01, xf10, xf11;
  {
    int xr0 = nh*32 + cc, xr1 = xr0 + 16;
    xf00 = *(const bf16x8*)(XbB + xr0*144 + (q*8)*2);
    xf01 = *(const bf16x8*)(XbB + xr0*144 + (32+q*8)*2);
    xf10 = *(const bf16x8*)(XbB + xr1*144 + (q*8)*2);
    xf11 = *(const bf16x8*)(XbB + xr1*144 + (32+q*8)*2);
  }

  // per-thread gather binding: row r (dst node), o-range dq*8..+7
  const int r = tid >> 3, dq = tid & 7;
  const int myo = offl[r], mydg = degl[r];
  const float* ehTg = ehT + (size_t)g*100;
  const int brow = tid >> 2, bpart = tid & 3;

  // prologue: chunk-0 B + eh(k=0,1)
  int4 br0, br1;
  {
    const unsigned short* src = W2n + (size_t)brow*64 + bpart*16;
    br0 = *(const int4*)src; br1 = *(const int4*)(src + 8);
  }
  float er0 = 0.f, er1 = 0.f;
  if (tid < 100) { er0 = ehTg[0*(size_t)N_EDGES + tid]; er1 = ehTg[1*(size_t)N_EDGES + tid]; }
  *(int4*)(BtB + brow*144 + (((bpart*2  )^(brow&7))<<4)) = br0;
  *(int4*)(BtB + brow*144 + (((bpart*2+1)^(brow&7))<<4)) = br1;
  if (tid < 100) { ehl[0][tid*2] = er0; ehl[0][tid*2+1] = er1; }
  __syncthreads();

  float fin0=0.f, fin1=0.f, fin2=0.f, fin3=0.f, fin4=0.f, fin5=0.f, fin6=0.f, fin7=0.f;

  #pragma unroll 1
  for (int c = 0; c < 64; ++c) {
    // ---- phase A: MFMA T_c + Tt write + prefetch-issue ----
    f32x4 tc00={}, tc01={}, tc10={}, tc11={};
    {
      int ar0 = mw*32 + cc, ar1 = ar0 + 16;
      #pragma unroll
      for (int ks = 0; ks < 2; ++ks) {
        bf16x8 af0 = *(const bf16x8*)(BtB + ar0*144 + (((ks*4+q)^(ar0&7))<<4));
        bf16x8 af1 = *(const bf16x8*)(BtB + ar1*144 + (((ks*4+q)^(ar1&7))<<4));
        bf16x8 xb0 = ks ? xf01 : xf00;
        bf16x8 xb1 = ks ? xf11 : xf10;
        tc00 = __builtin_amdgcn_mfma_f32_16x16x32_bf16(af0, xb0, tc00, 0,0,0);
        tc01 = __builtin_amdgcn_mfma_f32_16x16x32_bf16(af0, xb1, tc01, 0,0,0);
        tc10 = __builtin_amdgcn_mfma_f32_16x16x32_bf16(af1, xb0, tc10, 0,0,0);
        tc11 = __builtin_amdgcn_mfma_f32_16x16x32_bf16(af1, xb1, tc11, 0,0,0);
      }
    }
    {
      // D row = q*4+i2 -> n_loc = mw*32 + a*16 + q*4+i2 ; D col = cc -> s = nh*32 + b*16 + cc
      int n0a = mw*32 + q*4, n0b = n0a + 16;
      int sA = nh*32 + cc,   sB = sA + 16;
      float4 v;
      v.x=tc00[0]; v.y=tc00[1]; v.z=tc00[2]; v.w=tc00[3];
      *(float4*)&Tt[sA*132 + n0a] = v;
      v.x=tc01[0]; v.y=tc01[1]; v.z=tc01[2]; v.w=tc01[3];
      *(float4*)&Tt[sB*132 + n0a] = v;
      v.x=tc10[0]; v.y=tc10[1]; v.z=tc10[2]; v.w=tc10[3];
      *(float4*)&Tt[sA*132 + n0b] = v;
      v.x=tc11[0]; v.y=tc11[1]; v.z=tc11[2]; v.w=tc11[3];
      *(float4*)&Tt[sB*132 + n0b] = v;
    }
    if (c < 63) {
      const unsigned short* src = W2n + ((size_t)(c+1)*128 + brow)*64 + bpart*16;
      br0 = *(const int4*)src; br1 = *(const int4*)(src + 8);
      if (tid < 100) {
        er0 = ehTg[(size_t)(2*c+2)*N_EDGES + tid];
        er1 = ehTg[(size_t)(2*c+3)*N_EDGES + tid];
      }
    }
    __syncthreads();
    // ---- phase B: gather + next-chunk LDS writes ----
    {
      const float* ebuf = ehl[c & 1];
      for (int ii = 0; ii < mydg; ++ii) {
        int pk = sel[myo + ii];
        int s2 = pk & 0xffff, e2 = pk >> 16;
        float ex = ebuf[e2*2], ey = ebuf[e2*2+1];
        const float* tb = &Tt[s2*132];
        float4 ta0 = *(const float4*)(tb + dq*8);
        float4 ta1 = *(const float4*)(tb + dq*8 + 4);
        float4 tb0 = *(const float4*)(tb + 64 + dq*8);
        float4 tb1 = *(const float4*)(tb + 64 + dq*8 + 4);
        fin0 += ex*ta0.x + ey*tb0.x;  fin1 += ex*ta0.y + ey*tb0.y;
        fin2 += ex*ta0.z + ey*tb0.z;  fin3 += ex*ta0.w + ey*tb0.w;
        fin4 += ex*ta1.x + ey*tb1.x;  fin5 += ex*ta1.y + ey*tb1.y;
        fin6 += ex*ta1.z + ey*tb1.z;  fin7 += ex*ta1.w + ey*tb1.w;
      }
    }
    if (c < 63) {
      *(int4*)(BtB + brow*144 + (((bpart*2  )^(brow&7))<<4)) = br0;
      *(int4*)(BtB + brow*144 + (((bpart*2+1)^(brow&7))<<4)) = br1;
      if (tid < 100) { ehl[(c+1)&1][tid*2] = er0; ehl[(c+1)&1][tid*2+1] = er1; }
    }
    __syncthreads();
  }

  // ---- epilogue: + Q gather (global, prev step), write aggL (overlays BtB) ----
  {
    for (int ii = 0; ii < mydg; ++ii) {
      int s2 = sel[myo + ii] & 0xffff;
      const float* qp = Qb + (size_t)(g*50 + s2)*64 + dq*8;
      float4 q0 = *(const float4*)(qp);
      float4 q1 = *(const float4*)(qp + 4);
      fin0 += q0.x; fin1 += q0.y; fin2 += q0.z; fin3 += q0.w;
      fin4 += q1.x; fin5 += q1.y; fin6 += q1.z; fin7 += q1.w;
    }
    float4 f0 = {fin0, fin1, fin2, fin3};
    float4 f1 = {fin4, fin5, fin6, fin7};
    *(float4*)&aggL[r*66 + dq*8]     = f0;
    *(float4*)&aggL[r*66 + dq*8 + 4] = f1;
  }
  __syncthreads();

  // ---- GRU (round-4 k_upd math; 8 nodes/wave) ----
  {
    float ot[8];
    #pragma unroll
    for (int i = 0; i < 8; ++i) {
      int n = wave*8 + i;
      ot[i] = (n < 50) ? outf[(size_t)(g*50+n)*64 + t] : 0.f;
    }
    float mm[8];
    {
      float rc[8] = {0,0,0,0,0,0,0,0};
      for (int d = 0; d < 64; ++d) {
        float w = rootw[d*64+t];
        #pragma unroll
        for (int i = 0; i < 8; ++i) rc[i] += rl(ot[i], d) * w;
      }
      float cb = conv_b[t];
      #pragma unroll
      for (int i = 0; i < 8; ++i) {
        int n = wave*8 + i;
        mm[i] = lrelu(aggL[n*66 + t]*invd[n] + rc[i] + cb);
      }
    }
    float air[8]={}, aiz[8]={}, ain[8]={}, ahr[8]={}, ahz[8]={}, ahn[8]={};
    for (int d = 0; d < 64; ++d) {
      const float* wp = gw6 + (size_t)(d*64+t)*8;
      float4 w0 = *(const float4*)wp;
      float4 w1 = *(const float4*)(wp + 4);
      #pragma unroll
      for (int i = 0; i < 8; ++i) {
        float md = rl(mm[i], d), hd = rl(ot[i], d);
        air[i] += md*w0.x; aiz[i] += md*w0.y; ain[i] += md*w0.z;
        ahr[i] += hd*w0.w; ahz[i] += hd*w1.x; ahn[i] += hd*w1.y;
      }
    }
    float bi0 = bih[t], bi1 = bih[64+t], bi2 = bih[128+t];
    float bh0 = bhh[t], bh1 = bhh[64+t], bh2 = bhh[128+t];
    float h[8];
    #pragma unroll
    for (int i = 0; i < 8; ++i) {
      int n = wave*8 + i;
      float rg = sigm(air[i] + bi0 + ahr[i] + bh0);
      float zg = sigm(aiz[i] + bi1 + ahz[i] + bh1);
      float ng = tanhf(ain[i] + bi2 + rg*(ahn[i] + bh2));
      h[i] = (1.f - zg)*ng + zg*ot[i];
      if (n < 50) outf[(size_t)(g*50+n)*64 + t] = h[i];
    }
    float qa[8] = {0,0,0,0,0,0,0,0};
    for (int d = 0; d < 64; ++d) {
      float qw = net2_b[d*64+t];
      #pragma unroll
      for (int i = 0; i < 8; ++i) qa[i] += rl(h[i], d) * qw;
    }
    #pragma unroll
    for (int i = 0; i < 8; ++i) {
      int n = wave*8 + i;
      if (n < 50) Qb[(size_t)(g*50+n)*64 + t] = qa[i];
    }
  }
}

// ---------------- per-stem head ----------------
__global__ __launch_bounds__(256) void k_stem(const float* __restrict__ outf,
    const int* __restrict__ stems, const int* __restrict__ stems_batch,
    const float* __restrict__ l1T, const float* __restrict__ l1b,
    const float* __restrict__ l2T, const float* __restrict__ l2b,
    float* __restrict__ per_stem) {
  int t = threadIdx.x & 63;
  int s = blockIdx.x*4 + (threadIdx.x>>6);
  int node = stems_batch[s]*50 + stems[s];
  float sx = outf[node*64+t];
  float t1[8];
  #pragma unroll
  for (int g = 0; g < 8; ++g) t1[g] = l1b[g*64+t];
  for (int d = 0; d < 64; ++d) {
    float xd = __shfl(sx, d);
    const float* L = l1T + d*512 + t;
    #pragma unroll
    for (int g = 0; g < 8; ++g) t1[g] += xd * L[g*64];
  }
  #pragma unroll
  for (int g = 0; g < 8; ++g) t1[g] = lrelu(t1[g]);
  float a0 = l2b[t];
  float a1 = (t < 41) ? l2b[64+t] : 0.f;
  for (int g = 0; g < 8; ++g) {
    for (int d = 0; d < 64; ++d) {
      float tj = __shfl(t1[g], d);
      int j = g*64 + d;
      a0 += tj * l2T[j*105 + t];
      a1 += tj * ((t < 41) ? l2T[j*105 + 64 + t] : 0.f);
    }
  }
  per_stem[s*105 + t] = a0;
  if (t < 41) per_stem[s*105 + 64 + t] = a1;
}

// ---------------- Set2Set (3 LSTM-attention steps) + final linear ----------------
__global__ __launch_bounds__(64) void k_s2s(const float* __restrict__ outf,
    const float* __restrict__ wihT, const float* __restrict__ whhT,
    const float* __restrict__ bih, const float* __restrict__ bhh,
    const float* __restrict__ l3w, const float* __restrict__ l3b,
    float* __restrict__ sout) {
  int b = blockIdx.x, t = threadIdx.x;
  const float* og = outf + b*50*64;
  float qlo = 0.f, qhi = 0.f, hs = 0.f, cs = 0.f;
  float b0 = bih[t]+bhh[t], b1 = bih[64+t]+bhh[64+t], b2 = bih[128+t]+bhh[128+t], b3 = bih[192+t]+bhh[192+t];
  for (int it = 0; it < 3; ++it) {
    float g0 = b0, g1 = b1, g2 = b2, g3 = b3;
    for (int c = 0; c < 64; ++c) {
      float qc = __shfl(qlo, c);
      const float* L = wihT + c*256 + t;
      g0 += qc*L[0]; g1 += qc*L[64]; g2 += qc*L[128]; g3 += qc*L[192];
    }
    for (int c = 0; c < 64; ++c) {
      float qc = __shfl(qhi, c);
      const float* L = wihT + (64+c)*256 + t;
      g0 += qc*L[0]; g1 += qc*L[64]; g2 += qc*L[128]; g3 += qc*L[192];
    }
    for (int d = 0; d < 64; ++d) {
      float hd = __shfl(hs, d);
      const float* L = whhT + d*256 + t;
      g0 += hd*L[0]; g1 += hd*L[64]; g2 += hd*L[128]; g3 += hd*L[192];
    }
    float ig = sigm(g0), fg = sigm(g1), cg = tanhf(g2), oo = sigm(g3);
    cs = fg*cs + ig*cg;
    hs = oo*tanhf(cs);
    float ei = -3.4e38f;
    for (int i = 0; i < 50; ++i) {
      float p = og[i*64+t]*hs;
      #pragma unroll
      for (int m2 = 1; m2 < 64; m2 <<= 1) p += __shfl_xor(p, m2);
      if (t == i) ei = p;
    }
    float em = ei;
    #pragma unroll
    for (int m2 = 1; m2 < 64; m2 <<= 1) em = fmaxf(em, __shfl_xor(em, m2));
    float av = (t < 50) ? __expf(ei - em) : 0.f;
    float as = av;
    #pragma unroll
    for (int m2 = 1; m2 < 64; m2 <<= 1) as += __shfl_xor(as, m2);
    av /= as;
    float rr = 0.f;
    for (int i = 0; i < 50; ++i) rr += __shfl(av, i) * og[i*64+t];
    qlo = hs; qhi = rr;
  }
  float p = qlo*l3w[t] + qhi*l3w[64+t];
  #pragma unroll
  for (int m2 = 1; m2 < 64; m2 <<= 1) p += __shfl_xor(p, m2);
  if (t == 0) sout[b] = p + l3b[0];
}

extern "C" void kernel_launch(void* const* d_in, const int* in_sizes, int n_in,
                              void* d_out, int out_size, void* d_ws, size_t ws_size,
                              hipStream_t stream) {
  const float* x          = (const float*)d_in[0];
  const float* edge_attr  = (const float*)d_in[1];
  const int*   edge_index = (const int*)  d_in[2];
  const int*   stems      = (const int*)  d_in[4];
  const int*   stems_b    = (const int*)  d_in[5];
  const float* lin0_w = (const float*)d_in[6];
  const float* lin0_b = (const float*)d_in[7];
  const float* net1_w = (const float*)d_in[8];
  const float* net1_b = (const float*)d_in[9];
  const float* net2_w = (const float*)d_in[10];
  const float* net2_b = (const float*)d_in[11];
  const float* root_w = (const float*)d_in[12];
  const float* conv_b = (const float*)d_in[13];
  const float* gru_wih = (const float*)d_in[14];
  const float* gru_whh = (const float*)d_in[15];
  const float* gru_bih = (const float*)d_in[16];
  const float* gru_bhh = (const float*)d_in[17];
  const float* lin1_w = (const float*)d_in[18];
  const float* lin1_b = (const float*)d_in[19];
  const float* lin2_w = (const float*)d_in[20];
  const float* lin2_b = (const float*)d_in[21];
  const float* lstm_wih = (const float*)d_in[22];
  const float* lstm_whh = (const float*)d_in[23];
  const float* lstm_bih = (const float*)d_in[24];
  const float* lstm_bhh = (const float*)d_in[25];
  const float* lin3_w = (const float*)d_in[26];
  const float* lin3_b = (const float*)d_in[27];

  char* ws = (char*)d_ws;
  size_t off = 0;
  auto alloc = [&](size_t bytes) { void* p = ws + off; off += (bytes + 255) & ~(size_t)255; return p; };
  float* ehT  = (float*)alloc((size_t)N_EDGES*128*4);          // 26.2MB  [k][e]
  unsigned short* W2n = (unsigned short*)alloc(524288*2);      // 1MB
  float* outf = (float*)alloc((size_t)N_NODES*64*4);
  float* Qb   = (float*)alloc((size_t)N_NODES*64*4);
  int* deg  = (int*)alloc(N_NODES*4);
  int* offs = (int*)alloc(N_NODES*4);
  int* csr  = (int*)alloc(N_EDGES*4);
  float* gw6   = (float*)alloc(32768*4);
  float* lwihT = (float*)alloc(32768*4);
  float* lwhhT = (float*)alloc(16384*4);
  float* l1T   = (float*)alloc(32768*4);
  float* l2T   = (float*)alloc(53760*4);
  float* l0T   = (float*)alloc(1536*4);

  if (off > ws_size) {   // diagnosable fallback (signature absmax 1.5625e-1)
    hipMemsetAsync(d_out, 0, (size_t)out_size * sizeof(float), stream);
    return;
  }

  float* per_stem = (float*)d_out;
  float* sout = per_stem + 2560*105;

  k_prep<<<2712, 256, 0, stream>>>(net2_w, W2n, gru_wih, gru_whh, gw6,
                                   lstm_wih, lstm_whh, lwihT, lwhhT,
                                   lin1_w, l1T, lin2_w, l2T, lin0_w, l0T);
  k_lin0<<<N_NODES/4, 256, 0, stream>>>(x, l0T, lin0_b, net2_b, outf, Qb);
  k_eh<<<N_EDGES/64, 256, 0, stream>>>(edge_attr, net1_w, net1_b, ehT);
  k_csr<<<NG, 128, 0, stream>>>(edge_index, deg, offs, csr);
  for (int s = 0; s < 12; ++s) {
    k_step<<<NG, 512, 0, stream>>>(outf, ehT, W2n, Qb, edge_index, csr, offs, deg,
                                   root_w, conv_b, gw6, gru_bih, gru_bhh, net2_b);
  }
  k_stem<<<2560/4, 256, 0, stream>>>(outf, stems, stems_b, l1T, lin1_b, l2T, lin2_b, per_stem);
  k_s2s<<<NG, 64, 0, stream>>>(outf, lwihT, lwhhT, lstm_bih, lstm_bhh, lin3_w, lin3_b, sout);
}

// Round 8
// 2515.627 us; speedup vs baseline: 1.1111x; 1.1111x over previous
//
#include <hip/hip_runtime.h>
#include <hip/hip_bf16.h>
#include <stdint.h>

#define N_NODES 25600
#define N_EDGES 51200
#define NG      512

typedef __attribute__((ext_vector_type(4))) float f32x4;
typedef __attribute__((ext_vector_type(2))) float f32x2;
typedef __attribute__((ext_vector_type(8))) short bf16x8;

typedef union { float4 f4; f32x2 h[2]; } v4u;

__device__ __forceinline__ float lrelu(float v){ return v > 0.f ? v : 0.01f*v; }
__device__ __forceinline__ float sigm(float v){ return 1.f/(1.f+__expf(-v)); }
__device__ __forceinline__ unsigned short f2b(float v){
  union { float f; uint32_t u; } x; x.f = v;
  uint32_t u = x.u;
  return (unsigned short)((u + 0x7FFFu + ((u>>16)&1u)) >> 16);
}
__device__ __forceinline__ unsigned int pk2(float a, float b){
  unsigned int r;
  asm("v_cvt_pk_bf16_f32 %0, %1, %2" : "=v"(r) : "v"(a), "v"(b));
  return r;
}
__device__ __forceinline__ float rl(float v, int l){
  return __int_as_float(__builtin_amdgcn_readlane(__float_as_int(v), l));
}

// ---------------- prep ----------------
// W2n[(k*64+o)*64 + d] = bf16(net2_w[(d*64+o)*128 + k])   (8192 x 64)
// gw6[(d*64+t)*8 + j]  : j=0..2 gru_wih rows (r,z,n) col d; 3..5 gru_whh; 6,7 pad
__global__ void k_prep(const float* __restrict__ net2_w, unsigned short* __restrict__ W2n,
                       const float* __restrict__ gwih, const float* __restrict__ gwhh,
                       float* __restrict__ gw6,
                       const float* __restrict__ lwih, const float* __restrict__ lwhh,
                       float* __restrict__ lwihT, float* __restrict__ lwhhT,
                       const float* __restrict__ lin1w, float* __restrict__ l1T,
                       const float* __restrict__ lin2w, float* __restrict__ l2T,
                       const float* __restrict__ lin0w, float* __restrict__ l0T) {
  const int total = 524288+32768+32768+16384+32768+53760+1536;
  for (int i = blockIdx.x*blockDim.x + threadIdx.x; i < total; i += gridDim.x*blockDim.x) {
    int idx = i;
    if (idx < 524288) {
      int n = idx >> 6, d = idx & 63;
      int k = n >> 6, o = n & 63;
      W2n[idx] = f2b(net2_w[(d*64+o)*128 + k]);
      continue;
    }
    idx -= 524288;
    if (idx < 32768) {
      int dt = idx >> 3, j = idx & 7;
      int d = dt >> 6, t = dt & 63;
      float v = 0.f;
      if (j < 3) v = gwih[(j*64+t)*64 + d];
      else if (j < 6) v = gwhh[((j-3)*64+t)*64 + d];
      gw6[idx] = v; continue;
    }
    idx -= 32768;
    if (idx < 32768) { int c = idx/256, j = idx%256; lwihT[idx] = lwih[j*128+c]; continue; }
    idx -= 32768;
    if (idx < 16384) { int d = idx/256, j = idx%256; lwhhT[idx] = lwhh[j*64+d]; continue; }
    idx -= 16384;
    if (idx < 32768) { int d = idx/512, j = idx%512; l1T[idx] = lin1w[j*64+d]; continue; }
    idx -= 32768;
    if (idx < 53760) { int j = idx/105, o = idx%105; l2T[idx] = lin2w[o*512+j]; continue; }
    idx -= 53760;
    { int f = idx/64, o = idx%64; l0T[idx] = lin0w[o*24+f]; }
  }
}

// ---------------- lin0: out = lrelu(x @ lin0_w.T + b); Q0 = out @ b2mat ----------------
__global__ __launch_bounds__(256) void k_lin0(const float* __restrict__ x, const float* __restrict__ l0T,
     const float* __restrict__ b, const float* __restrict__ net2_b,
     float* __restrict__ outf, float* __restrict__ Q) {
  int t = threadIdx.x & 63;
  int n = blockIdx.x*4 + (threadIdx.x>>6);
  float xv = (t < 24) ? x[n*24+t] : 0.f;
  float acc = b[t];
  #pragma unroll
  for (int f = 0; f < 24; ++f) acc += __shfl(xv, f) * l0T[f*64+t];
  acc = lrelu(acc);
  outf[n*64+t] = acc;
  float qa = 0.f;
  #pragma unroll 8
  for (int d = 0; d < 64; ++d) qa += __shfl(acc, d) * net2_b[d*64+t];
  Q[n*64+t] = qa;
}

// ---------------- ehP[c][e][kl] = lrelu(edge_attr @ net1_w.T + b), k = 2c+kl ----------------
__global__ __launch_bounds__(256) void k_eh(const float* __restrict__ ea, const float* __restrict__ w,
    const float* __restrict__ b, float* __restrict__ ehP) {
  __shared__ float tile[128][65];
  int e0 = blockIdx.x*64;
  int tid = threadIdx.x;
  #pragma unroll
  for (int r = 0; r < 32; ++r) {
    int idx = tid + r*256; int el = idx >> 7, k = idx & 127;
    float4 a = *(const float4*)(ea + (size_t)(e0+el)*4);
    float4 ww = *(const float4*)(w + k*4);
    tile[k][el] = lrelu(a.x*ww.x + a.y*ww.y + a.z*ww.z + a.w*ww.w + b[k]);
  }
  __syncthreads();
  #pragma unroll
  for (int r = 0; r < 32; ++r) {
    int idx = tid + r*256; int k = idx >> 6, el = idx & 63;
    ehP[((size_t)(k>>1)*N_EDGES + e0 + el)*2 + (k&1)] = tile[k][el];
  }
}

// ---------------- deterministic per-graph CSR by dst ----------------
__global__ __launch_bounds__(128) void k_csr(const int* __restrict__ ei, int* __restrict__ deg,
                                             int* __restrict__ off, int* __restrict__ csr) {
  __shared__ int cnt[50];
  __shared__ int cur[50];
  __shared__ int dloc[100];
  int g = blockIdx.x, t = threadIdx.x;
  const int* dst = ei + N_EDGES;
  if (t < 50) cnt[t] = 0;
  __syncthreads();
  if (t < 100) { dloc[t] = dst[g*100+t] - g*50; atomicAdd(&cnt[dloc[t]], 1); }
  __syncthreads();
  if (t == 0) { int run = 0; for (int i = 0; i < 50; ++i) { cur[i] = run; run += cnt[i]; } }
  __syncthreads();
  if (t < 50) { deg[g*50+t] = cnt[t]; off[g*50+t] = g*100 + cur[t]; }
  __syncthreads();
  if (t < 100) {
    int p = 0, me = dloc[t];
    for (int i = 0; i < t; ++i) p += (dloc[i] == me);   // deterministic rank
    csr[g*100 + cur[me] + p] = g*100 + t;
  }
}

// ---------------- per-step: T-form bilinear conv + GRU, 1 graph/block ----------------
__global__ __launch_bounds__(512, 4) void k_step(
    float* __restrict__ outf, const float* __restrict__ ehP,
    const unsigned short* __restrict__ W2n, float* __restrict__ Qb,
    const int* __restrict__ ei, const int* __restrict__ csr,
    const int* __restrict__ offs, const int* __restrict__ deg,
    const float* __restrict__ rootw, const float* __restrict__ conv_b,
    const float* __restrict__ gw6, const float* __restrict__ bih, const float* __restrict__ bhh,
    const float* __restrict__ net2_b) {
  __shared__ __align__(16) char  BtB[128*128];   // W2 chunk bf16 [n_loc][d], 8x16B slots, slot ^= (row&7)
  __shared__ __align__(16) float Tt[64*132];     // T f32 [s][128 + pad4]; reused as aggL [64][66]
  __shared__ f32x2 ehl2[2][112];                 // packed eh pairs per chunk
  __shared__ int sel[100];
  __shared__ int offl[64];
  __shared__ int degl[64];
  __shared__ float invd[64];
  float* aggL = Tt;

  const int tid = threadIdx.x;
  const int g = blockIdx.x;
  const int wave = tid >> 6, lane = tid & 63;
  const int t = lane;
  const int q = lane >> 4, cc = lane & 15;
  const int mw = wave >> 1, nh = wave & 1;

  // ---- stage meta ----
  if (tid < 64) {
    int dgv = 0, ofv = 0;
    if (tid < 50) { dgv = deg[g*50+tid]; ofv = offs[g*50+tid] - g*100; }
    degl[tid] = dgv; offl[tid] = ofv;
    invd[tid] = 1.f/(float)(dgv > 0 ? dgv : 1);
  }
  if (tid < 100) {
    int eg = csr[g*100+tid];
    sel[tid] = (ei[eg]-g*50) | ((eg-g*100) << 16);
  }
  // prologue global issues (no LDS dep)
  const int brow = tid >> 2, bpart = tid & 3;
  const float* ehPg = ehP + (size_t)g*100*2;
  int4 br0, br1;
  {
    const unsigned short* src = W2n + (size_t)brow*64 + bpart*16;
    br0 = *(const int4*)src; br1 = *(const int4*)(src + 8);
  }
  f32x2 er = {0.f, 0.f};
  if (tid < 100) er = *(const f32x2*)(ehPg + tid*2);
  __syncthreads();

  // per-thread gather binding: row r (dst node), o-range dq*8..+7
  const int r = tid >> 3, dq = tid & 7;
  const int myo = offl[r], mydg = degl[r];
  int se0=0, se1=0, se2=0, se3=0;
  if (mydg > 0) se0 = sel[myo];
  if (mydg > 1) se1 = sel[myo+1];
  if (mydg > 2) se2 = sel[myo+2];
  if (mydg > 3) se3 = sel[myo+3];

  // X fragments in registers (chunk-invariant): from global outf, pk2 (RTNE)
  bf16x8 xf00, xf01, xf10, xf11;
  {
    int xr0 = nh*32 + cc, xr1 = xr0 + 16;
    union { bf16x8 v; uint u[4]; } X;
    #pragma unroll
    for (int half = 0; half < 4; ++half) {
      int row = (half & 1) ? xr1 : xr0;
      int d0  = (half & 2) ? (32 + q*8) : (q*8);
      if (row < 50) {
        const float* p = outf + (size_t)(g*50+row)*64 + d0;
        float4 a = *(const float4*)p;
        float4 b = *(const float4*)(p+4);
        X.u[0]=pk2(a.x,a.y); X.u[1]=pk2(a.z,a.w); X.u[2]=pk2(b.x,b.y); X.u[3]=pk2(b.z,b.w);
      } else { X.u[0]=0; X.u[1]=0; X.u[2]=0; X.u[3]=0; }
      if (half==0) xf00=X.v; else if (half==1) xf10=X.v; else if (half==2) xf01=X.v; else xf11=X.v;
    }
  }

  // prologue LDS writes: chunk-0 B + eh pair
  *(int4*)(BtB + (brow<<7) + (((bpart*2  )^(brow&7))<<4)) = br0;
  *(int4*)(BtB + (brow<<7) + (((bpart*2+1)^(brow&7))<<4)) = br1;
  if (tid < 100) ehl2[0][tid] = er;
  __syncthreads();

  f32x2 fin01={0,0}, fin23={0,0}, fin45={0,0}, fin67={0,0};

  #pragma unroll 1
  for (int c = 0; c < 64; ++c) {
    // ---- phase A: MFMA T_c + Tt write + prefetch-issue ----
    f32x4 tc00={}, tc01={}, tc10={}, tc11={};
    {
      int ar0 = mw*32 + cc, ar1 = ar0 + 16;
      #pragma unroll
      for (int ks = 0; ks < 2; ++ks) {
        bf16x8 af0 = *(const bf16x8*)(BtB + (ar0<<7) + (((ks*4+q)^(ar0&7))<<4));
        bf16x8 af1 = *(const bf16x8*)(BtB + (ar1<<7) + (((ks*4+q)^(ar1&7))<<4));
        bf16x8 xb0 = ks ? xf01 : xf00;
        bf16x8 xb1 = ks ? xf11 : xf10;
        tc00 = __builtin_amdgcn_mfma_f32_16x16x32_bf16(af0, xb0, tc00, 0,0,0);
        tc01 = __builtin_amdgcn_mfma_f32_16x16x32_bf16(af0, xb1, tc01, 0,0,0);
        tc10 = __builtin_amdgcn_mfma_f32_16x16x32_bf16(af1, xb0, tc10, 0,0,0);
        tc11 = __builtin_amdgcn_mfma_f32_16x16x32_bf16(af1, xb1, tc11, 0,0,0);
      }
    }
    {
      int n0a = mw*32 + q*4, n0b = n0a + 16;
      int sA = nh*32 + cc,   sB = sA + 16;
      float4 v;
      v.x=tc00[0]; v.y=tc00[1]; v.z=tc00[2]; v.w=tc00[3];
      *(float4*)&Tt[sA*132 + n0a] = v;
      v.x=tc01[0]; v.y=tc01[1]; v.z=tc01[2]; v.w=tc01[3];
      *(float4*)&Tt[sB*132 + n0a] = v;
      v.x=tc10[0]; v.y=tc10[1]; v.z=tc10[2]; v.w=tc10[3];
      *(float4*)&Tt[sA*132 + n0b] = v;
      v.x=tc11[0]; v.y=tc11[1]; v.z=tc11[2]; v.w=tc11[3];
      *(float4*)&Tt[sB*132 + n0b] = v;
    }
    if (c < 63) {
      const unsigned short* src = W2n + ((size_t)(c+1)*128 + brow)*64 + bpart*16;
      br0 = *(const int4*)src; br1 = *(const int4*)(src + 8);
      if (tid < 100) er = *(const f32x2*)(ehPg + (size_t)(c+1)*N_EDGES*2 + tid*2);
    }
    __syncthreads();
    // ---- phase B: gather (packed f32x2 FMA) + next-chunk LDS writes ----
    {
      const f32x2* ebuf = ehl2[c & 1];
      for (int ii = 0; ii < mydg; ++ii) {
        int pk = (ii==0)?se0:(ii==1)?se1:(ii==2)?se2:(ii==3)?se3:sel[myo+ii];
        int s2 = pk & 0xffff, e2 = pk >> 16;
        f32x2 ep = ebuf[e2];
        const float* tb = &Tt[s2*132 + dq*8];
        v4u a0, a1, b0, b1;
        a0.f4 = *(const float4*)(tb);
        a1.f4 = *(const float4*)(tb + 4);
        b0.f4 = *(const float4*)(tb + 64);
        b1.f4 = *(const float4*)(tb + 68);
        f32x2 ex = {ep.x, ep.x}, ey = {ep.y, ep.y};
        fin01 += a0.h[0]*ex + b0.h[0]*ey;
        fin23 += a0.h[1]*ex + b0.h[1]*ey;
        fin45 += a1.h[0]*ex + b1.h[0]*ey;
        fin67 += a1.h[1]*ex + b1.h[1]*ey;
      }
    }
    if (c < 63) {
      *(int4*)(BtB + (brow<<7) + (((bpart*2  )^(brow&7))<<4)) = br0;
      *(int4*)(BtB + (brow<<7) + (((bpart*2+1)^(brow&7))<<4)) = br1;
      if (tid < 100) ehl2[(c+1)&1][tid] = er;
    }
    __syncthreads();
  }

  // ---- epilogue: + Q gather (global, prev step), write aggL (overlays Tt) ----
  {
    for (int ii = 0; ii < mydg; ++ii) {
      int pk = (ii==0)?se0:(ii==1)?se1:(ii==2)?se2:(ii==3)?se3:sel[myo+ii];
      int s2 = pk & 0xffff;
      const float* qp = Qb + (size_t)(g*50 + s2)*64 + dq*8;
      v4u q0, q1;
      q0.f4 = *(const float4*)(qp);
      q1.f4 = *(const float4*)(qp + 4);
      fin01 += q0.h[0]; fin23 += q0.h[1];
      fin45 += q1.h[0]; fin67 += q1.h[1];
    }
    float4 f0 = {fin01.x, fin01.y, fin23.x, fin23.y};
    float4 f1 = {fin45.x, fin45.y, fin67.x, fin67.y};
    *(float4*)&aggL[r*66 + dq*8]     = f0;
    *(float4*)&aggL[r*66 + dq*8 + 4] = f1;
  }
  __syncthreads();

  // ---- GRU (8 nodes/wave) ----
  {
    float ot[8];
    #pragma unroll
    for (int i = 0; i < 8; ++i) {
      int n = wave*8 + i;
      ot[i] = (n < 50) ? outf[(size_t)(g*50+n)*64 + t] : 0.f;
    }
    float mm[8];
    {
      float rc[8] = {0,0,0,0,0,0,0,0};
      for (int d = 0; d < 64; ++d) {
        float w = rootw[d*64+t];
        #pragma unroll
        for (int i = 0; i < 8; ++i) rc[i] += rl(ot[i], d) * w;
      }
      float cb = conv_b[t];
      #pragma unroll
      for (int i = 0; i < 8; ++i) {
        int n = wave*8 + i;
        mm[i] = lrelu(aggL[n*66 + t]*invd[n] + rc[i] + cb);
      }
    }
    float air[8]={}, aiz[8]={}, ain[8]={}, ahr[8]={}, ahz[8]={}, ahn[8]={};
    for (int d = 0; d < 64; ++d) {
      const float* wp = gw6 + (size_t)(d*64+t)*8;
      float4 w0 = *(const float4*)wp;
      float4 w1 = *(const float4*)(wp + 4);
      #pragma unroll
      for (int i = 0; i < 8; ++i) {
        float md = rl(mm[i], d), hd = rl(ot[i], d);
        air[i] += md*w0.x; aiz[i] += md*w0.y; ain[i] += md*w0.z;
        ahr[i] += hd*w0.w; ahz[i] += hd*w1.x; ahn[i] += hd*w1.y;
      }
    }
    float bi0 = bih[t], bi1 = bih[64+t], bi2 = bih[128+t];
    float bh0 = bhh[t], bh1 = bhh[64+t], bh2 = bhh[128+t];
    float h[8];
    #pragma unroll
    for (int i = 0; i < 8; ++i) {
      int n = wave*8 + i;
      float rg = sigm(air[i] + bi0 + ahr[i] + bh0);
      float zg = sigm(aiz[i] + bi1 + ahz[i] + bh1);
      float ng = tanhf(ain[i] + bi2 + rg*(ahn[i] + bh2));
      h[i] = (1.f - zg)*ng + zg*ot[i];
      if (n < 50) outf[(size_t)(g*50+n)*64 + t] = h[i];
    }
    float qa[8] = {0,0,0,0,0,0,0,0};
    for (int d = 0; d < 64; ++d) {
      float qw = net2_b[d*64+t];
      #pragma unroll
      for (int i = 0; i < 8; ++i) qa[i] += rl(h[i], d) * qw;
    }
    #pragma unroll
    for (int i = 0; i < 8; ++i) {
      int n = wave*8 + i;
      if (n < 50) Qb[(size_t)(g*50+n)*64 + t] = qa[i];
    }
  }
}

// ---------------- per-stem head ----------------
__global__ __launch_bounds__(256) void k_stem(const float* __restrict__ outf,
    const int* __restrict__ stems, const int* __restrict__ stems_batch,
    const float* __restrict__ l1T, const float* __restrict__ l1b,
    const float* __restrict__ l2T, const float* __restrict__ l2b,
    float* __restrict__ per_stem) {
  int t = threadIdx.x & 63;
  int s = blockIdx.x*4 + (threadIdx.x>>6);
  int node = stems_batch[s]*50 + stems[s];
  float sx = outf[node*64+t];
  float t1[8];
  #pragma unroll
  for (int g = 0; g < 8; ++g) t1[g] = l1b[g*64+t];
  for (int d = 0; d < 64; ++d) {
    float xd = __shfl(sx, d);
    const float* L = l1T + d*512 + t;
    #pragma unroll
    for (int g = 0; g < 8; ++g) t1[g] += xd * L[g*64];
  }
  #pragma unroll
  for (int g = 0; g < 8; ++g) t1[g] = lrelu(t1[g]);
  float a0 = l2b[t];
  float a1 = (t < 41) ? l2b[64+t] : 0.f;
  for (int g = 0; g < 8; ++g) {
    for (int d = 0; d < 64; ++d) {
      float tj = __shfl(t1[g], d);
      int j = g*64 + d;
      a0 += tj * l2T[j*105 + t];
      a1 += tj * ((t < 41) ? l2T[j*105 + 64 + t] : 0.f);
    }
  }
  per_stem[s*105 + t] = a0;
  if (t < 41) per_stem[s*105 + 64 + t] = a1;
}

// ---------------- Set2Set (3 LSTM-attention steps) + final linear ----------------
__global__ __launch_bounds__(64) void k_s2s(const float* __restrict__ outf,
    const float* __restrict__ wihT, const float* __restrict__ whhT,
    const float* __restrict__ bih, const float* __restrict__ bhh,
    const float* __restrict__ l3w, const float* __restrict__ l3b,
    float* __restrict__ sout) {
  int b = blockIdx.x, t = threadIdx.x;
  const float* og = outf + b*50*64;
  float qlo = 0.f, qhi = 0.f, hs = 0.f, cs = 0.f;
  float b0 = bih[t]+bhh[t], b1 = bih[64+t]+bhh[64+t], b2 = bih[128+t]+bhh[128+t], b3 = bih[192+t]+bhh[192+t];
  for (int it = 0; it < 3; ++it) {
    float g0 = b0, g1 = b1, g2 = b2, g3 = b3;
    for (int c = 0; c < 64; ++c) {
      float qc = __shfl(qlo, c);
      const float* L = wihT + c*256 + t;
      g0 += qc*L[0]; g1 += qc*L[64]; g2 += qc*L[128]; g3 += qc*L[192];
    }
    for (int c = 0; c < 64; ++c) {
      float qc = __shfl(qhi, c);
      const float* L = wihT + (64+c)*256 + t;
      g0 += qc*L[0]; g1 += qc*L[64]; g2 += qc*L[128]; g3 += qc*L[192];
    }
    for (int d = 0; d < 64; ++d) {
      float hd = __shfl(hs, d);
      const float* L = whhT + d*256 + t;
      g0 += hd*L[0]; g1 += hd*L[64]; g2 += hd*L[128]; g3 += hd*L[192];
    }
    float ig = sigm(g0), fg = sigm(g1), cg = tanhf(g2), oo = sigm(g3);
    cs = fg*cs + ig*cg;
    hs = oo*tanhf(cs);
    float ei = -3.4e38f;
    for (int i = 0; i < 50; ++i) {
      float p = og[i*64+t]*hs;
      #pragma unroll
      for (int m2 = 1; m2 < 64; m2 <<= 1) p += __shfl_xor(p, m2);
      if (t == i) ei = p;
    }
    float em = ei;
    #pragma unroll
    for (int m2 = 1; m2 < 64; m2 <<= 1) em = fmaxf(em, __shfl_xor(em, m2));
    float av = (t < 50) ? __expf(ei - em) : 0.f;
    float as = av;
    #pragma unroll
    for (int m2 = 1; m2 < 64; m2 <<= 1) as += __shfl_xor(as, m2);
    av /= as;
    float rr = 0.f;
    for (int i = 0; i < 50; ++i) rr += __shfl(av, i) * og[i*64+t];
    qlo = hs; qhi = rr;
  }
  float p = qlo*l3w[t] + qhi*l3w[64+t];
  #pragma unroll
  for (int m2 = 1; m2 < 64; m2 <<= 1) p += __shfl_xor(p, m2);
  if (t == 0) sout[b] = p + l3b[0];
}

extern "C" void kernel_launch(void* const* d_in, const int* in_sizes, int n_in,
                              void* d_out, int out_size, void* d_ws, size_t ws_size,
                              hipStream_t stream) {
  const float* x          = (const float*)d_in[0];
  const float* edge_attr  = (const float*)d_in[1];
  const int*   edge_index = (const int*)  d_in[2];
  const int*   stems      = (const int*)  d_in[4];
  const int*   stems_b    = (const int*)  d_in[5];
  const float* lin0_w = (const float*)d_in[6];
  const float* lin0_b = (const float*)d_in[7];
  const float* net1_w = (const float*)d_in[8];
  const float* net1_b = (const float*)d_in[9];
  const float* net2_w = (const float*)d_in[10];
  const float* net2_b = (const float*)d_in[11];
  const float* root_w = (const float*)d_in[12];
  const float* conv_b = (const float*)d_in[13];
  const float* gru_wih = (const float*)d_in[14];
  const float* gru_whh = (const float*)d_in[15];
  const float* gru_bih = (const float*)d_in[16];
  const float* gru_bhh = (const float*)d_in[17];
  const float* lin1_w = (const float*)d_in[18];
  const float* lin1_b = (const float*)d_in[19];
  const float* lin2_w = (const float*)d_in[20];
  const float* lin2_b = (const float*)d_in[21];
  const float* lstm_wih = (const float*)d_in[22];
  const float* lstm_whh = (const float*)d_in[23];
  const float* lstm_bih = (const float*)d_in[24];
  const float* lstm_bhh = (const float*)d_in[25];
  const float* lin3_w = (const float*)d_in[26];
  const float* lin3_b = (const float*)d_in[27];

  char* ws = (char*)d_ws;
  size_t off = 0;
  auto alloc = [&](size_t bytes) { void* p = ws + off; off += (bytes + 255) & ~(size_t)255; return p; };
  float* ehP  = (float*)alloc((size_t)N_EDGES*128*4);          // 26.2MB  [c][e][2]
  unsigned short* W2n = (unsigned short*)alloc(524288*2);      // 1MB
  float* outf = (float*)alloc((size_t)N_NODES*64*4);
  float* Qb   = (float*)alloc((size_t)N_NODES*64*4);
  int* deg  = (int*)alloc(N_NODES*4);
  int* offs = (int*)alloc(N_NODES*4);
  int* csr  = (int*)alloc(N_EDGES*4);
  float* gw6   = (float*)alloc(32768*4);
  float* lwihT = (float*)alloc(32768*4);
  float* lwhhT = (float*)alloc(16384*4);
  float* l1T   = (float*)alloc(32768*4);
  float* l2T   = (float*)alloc(53760*4);
  float* l0T   = (float*)alloc(1536*4);

  if (off > ws_size) {   // diagnosable fallback (signature absmax 1.5625e-1)
    hipMemsetAsync(d_out, 0, (size_t)out_size * sizeof(float), stream);
    return;
  }

  float* per_stem = (float*)d_out;
  float* sout = per_stem + 2560*105;

  k_prep<<<2712, 256, 0, stream>>>(net2_w, W2n, gru_wih, gru_whh, gw6,
                                   lstm_wih, lstm_whh, lwihT, lwhhT,
                                   lin1_w, l1T, lin2_w, l2T, lin0_w, l0T);
  k_lin0<<<N_NODES/4, 256, 0, stream>>>(x, l0T, lin0_b, net2_b, outf, Qb);
  k_eh<<<N_EDGES/64, 256, 0, stream>>>(edge_attr, net1_w, net1_b, ehP);
  k_csr<<<NG, 128, 0, stream>>>(edge_index, deg, offs, csr);
  for (int s = 0; s < 12; ++s) {
    k_step<<<NG, 512, 0, stream>>>(outf, ehP, W2n, Qb, edge_index, csr, offs, deg,
                                   root_w, conv_b, gw6, gru_bih, gru_bhh, net2_b);
  }
  k_stem<<<2560/4, 256, 0, stream>>>(outf, stems, stems_b, l1T, lin1_b, l2T, lin2_b, per_stem);
  k_s2s<<<NG, 64, 0, stream>>>(outf, lwihT, lwhhT, lstm_bih, lstm_bhh, lin3_w, lin3_b, sout);
}

// Round 12
// 2406.555 us; speedup vs baseline: 1.1615x; 1.0453x over previous
//
#include <hip/hip_runtime.h>
#include <hip/hip_bf16.h>
#include <stdint.h>

#define N_NODES 25600
#define N_EDGES 51200
#define NG      512

typedef __attribute__((ext_vector_type(4))) float f32x4;
typedef __attribute__((ext_vector_type(2))) float f32x2;
typedef __attribute__((ext_vector_type(8))) short bf16x8;

__device__ __forceinline__ float lrelu(float v){ return v > 0.f ? v : 0.01f*v; }
__device__ __forceinline__ float sigm(float v){ return 1.f/(1.f+__expf(-v)); }
__device__ __forceinline__ unsigned short f2b(float v){
  union { float f; uint32_t u; } x; x.f = v;
  uint32_t u = x.u;
  return (unsigned short)((u + 0x7FFFu + ((u>>16)&1u)) >> 16);
}
__device__ __forceinline__ unsigned int pk2(float a, float b){
  unsigned int r;
  asm("v_cvt_pk_bf16_f32 %0, %1, %2" : "=v"(r) : "v"(a), "v"(b));
  return r;
}
__device__ __forceinline__ float rl(float v, int l){
  return __int_as_float(__builtin_amdgcn_readlane(__float_as_int(v), l));
}

// ---------------- prep ----------------
// W2n[(k*64+o)*64 + d] = bf16(net2_w[(d*64+o)*128 + k])   (8192 x 64)
// gw6[(d*64+t)*8 + j]  : j=0..2 gru_wih rows (r,z,n) col d; 3..5 gru_whh; 6,7 pad
__global__ void k_prep(const float* __restrict__ net2_w, unsigned short* __restrict__ W2n,
                       const float* __restrict__ gwih, const float* __restrict__ gwhh,
                       float* __restrict__ gw6,
                       const float* __restrict__ lwih, const float* __restrict__ lwhh,
                       float* __restrict__ lwihT, float* __restrict__ lwhhT,
                       const float* __restrict__ lin1w, float* __restrict__ l1T,
                       const float* __restrict__ lin2w, float* __restrict__ l2T,
                       const float* __restrict__ lin0w, float* __restrict__ l0T) {
  const int total = 524288+32768+32768+16384+32768+53760+1536;
  for (int i = blockIdx.x*blockDim.x + threadIdx.x; i < total; i += gridDim.x*blockDim.x) {
    int idx = i;
    if (idx < 524288) {
      int n = idx >> 6, d = idx & 63;
      int k = n >> 6, o = n & 63;
      W2n[idx] = f2b(net2_w[(d*64+o)*128 + k]);
      continue;
    }
    idx -= 524288;
    if (idx < 32768) {
      int dt = idx >> 3, j = idx & 7;
      int d = dt >> 6, t = dt & 63;
      float v = 0.f;
      if (j < 3) v = gwih[(j*64+t)*64 + d];
      else if (j < 6) v = gwhh[((j-3)*64+t)*64 + d];
      gw6[idx] = v; continue;
    }
    idx -= 32768;
    if (idx < 32768) { int c = idx/256, j = idx%256; lwihT[idx] = lwih[j*128+c]; continue; }
    idx -= 32768;
    if (idx < 16384) { int d = idx/256, j = idx%256; lwhhT[idx] = lwhh[j*64+d]; continue; }
    idx -= 16384;
    if (idx < 32768) { int d = idx/512, j = idx%512; l1T[idx] = lin1w[j*64+d]; continue; }
    idx -= 32768;
    if (idx < 53760) { int j = idx/105, o = idx%105; l2T[idx] = lin2w[o*512+j]; continue; }
    idx -= 53760;
    { int f = idx/64, o = idx%64; l0T[idx] = lin0w[o*24+f]; }
  }
}

// ---------------- lin0: out = lrelu(x @ lin0_w.T + b) ----------------
__global__ __launch_bounds__(256) void k_lin0(const float* __restrict__ x, const float* __restrict__ l0T,
     const float* __restrict__ b, float* __restrict__ outf) {
  int t = threadIdx.x & 63;
  int n = blockIdx.x*4 + (threadIdx.x>>6);
  float xv = (t < 24) ? x[n*24+t] : 0.f;
  float acc = b[t];
  #pragma unroll
  for (int f = 0; f < 24; ++f) acc += __shfl(xv, f) * l0T[f*64+t];
  outf[n*64+t] = lrelu(acc);
}

// ---------------- ehP[c][e][kl] = lrelu(edge_attr @ net1_w.T + b), k = 2c+kl ----------------
__global__ __launch_bounds__(256) void k_eh(const float* __restrict__ ea, const float* __restrict__ w,
    const float* __restrict__ b, float* __restrict__ ehP) {
  __shared__ float tile[128][65];
  int e0 = blockIdx.x*64;
  int tid = threadIdx.x;
  #pragma unroll
  for (int r = 0; r < 32; ++r) {
    int idx = tid + r*256; int el = idx >> 7, k = idx & 127;
    float4 a = *(const float4*)(ea + (size_t)(e0+el)*4);
    float4 ww = *(const float4*)(w + k*4);
    tile[k][el] = lrelu(a.x*ww.x + a.y*ww.y + a.z*ww.z + a.w*ww.w + b[k]);
  }
  __syncthreads();
  #pragma unroll
  for (int r = 0; r < 32; ++r) {
    int idx = tid + r*256; int k = idx >> 6, el = idx & 63;
    ehP[((size_t)(k>>1)*N_EDGES + e0 + el)*2 + (k&1)] = tile[k][el];
  }
}

// ---------------- deterministic per-graph CSR by dst ----------------
__global__ __launch_bounds__(128) void k_csr(const int* __restrict__ ei, int* __restrict__ deg,
                                             int* __restrict__ off, int* __restrict__ csr) {
  __shared__ int cnt[50];
  __shared__ int cur[50];
  __shared__ int dloc[100];
  int g = blockIdx.x, t = threadIdx.x;
  const int* dst = ei + N_EDGES;
  if (t < 50) cnt[t] = 0;
  __syncthreads();
  if (t < 100) { dloc[t] = dst[g*100+t] - g*50; atomicAdd(&cnt[dloc[t]], 1); }
  __syncthreads();
  if (t == 0) { int run = 0; for (int i = 0; i < 50; ++i) { cur[i] = run; run += cnt[i]; } }
  __syncthreads();
  if (t < 50) { deg[g*50+t] = cnt[t]; off[g*50+t] = g*100 + cur[t]; }
  __syncthreads();
  if (t < 100) {
    int p = 0, me = dloc[t];
    for (int i = 0; i < t; ++i) p += (dloc[i] == me);   // deterministic rank
    csr[g*100 + cur[me] + p] = g*100 + t;
  }
}

// ---------------- fused 12-step conv: round-8 per-step body, h/Q in LDS ----------------
__global__ __launch_bounds__(512, 4) void k_conv(
    float* __restrict__ outf, const float* __restrict__ ehP,
    const unsigned short* __restrict__ W2n,
    const int* __restrict__ ei, const int* __restrict__ csr,
    const int* __restrict__ offs, const int* __restrict__ deg,
    const float* __restrict__ rootw, const float* __restrict__ conv_b,
    const float* __restrict__ gw6, const float* __restrict__ bih,
    const float* __restrict__ bhh, const float* __restrict__ net2_b) {
  __shared__ __align__(16) char  BtB[128*128];   // W2 chunk bf16, 8x16B slots, slot ^= (row&7)
  __shared__ __align__(16) float Tt[64*132];     // T f32 [s][128 + pad]; reused as aggL [64][66]
  __shared__ f32x2 ehl2[2][112];                 // packed eh pairs per chunk (dbuf)
  __shared__ int sel[100];
  __shared__ int offl[64];
  __shared__ int degl[64];
  __shared__ float invd[64];
  __shared__ __align__(16) float hf[50*64];      // h state (block-local across steps)
  __shared__ __align__(16) float Ql[50*64];      // Q = h @ b2mat (block-local)
  float* aggL = Tt;

  const int tid = threadIdx.x;
  const int g = blockIdx.x;
  const int wave = tid >> 6, lane = tid & 63;
  const int t = lane;
  const int q = lane >> 4, cc = lane & 15;
  const int mw = wave >> 1, nh = wave & 1;

  // ---- stage meta + h0 ----
  if (tid < 64) {
    int dgv = 0, ofv = 0;
    if (tid < 50) { dgv = deg[g*50+tid]; ofv = offs[g*50+tid] - g*100; }
    degl[tid] = dgv; offl[tid] = ofv;
    invd[tid] = 1.f/(float)(dgv > 0 ? dgv : 1);
  }
  if (tid < 100) {
    int eg = csr[g*100+tid];
    sel[tid] = (ei[eg]-g*50) | ((eg-g*100) << 16);
  }
  for (int i = tid; i < 3200; i += 512) hf[i] = outf[(size_t)g*3200 + i];
  __syncthreads();

  // per-thread gather binding: row r (dst node), o-range dq*8..+7
  const int r = tid >> 3, dq = tid & 7;
  const int myo = offl[r], mydg = degl[r];
  int se0=0, se1=0, se2=0, se3=0;
  if (mydg > 0) se0 = sel[myo];
  if (mydg > 1) se1 = sel[myo+1];
  if (mydg > 2) se2 = sel[myo+2];
  if (mydg > 3) se3 = sel[myo+3];

  // ---- Q0 -> Ql ----
  {
    float hcur[8];
    #pragma unroll
    for (int i = 0; i < 8; ++i) {
      int n = wave*8 + i;
      hcur[i] = (n < 50) ? hf[n*64+t] : 0.f;
    }
    float qa[8] = {0,0,0,0,0,0,0,0};
    for (int d = 0; d < 64; ++d) {
      float qw = net2_b[d*64+t];
      #pragma unroll
      for (int i = 0; i < 8; ++i) qa[i] += rl(hcur[i], d) * qw;
    }
    #pragma unroll
    for (int i = 0; i < 8; ++i) {
      int n = wave*8 + i;
      if (n < 50) Ql[n*64+t] = qa[i];
    }
  }
  __syncthreads();

  const float* ehPg = ehP + (size_t)g*100*2;
  const int brow = tid >> 2, bpart = tid & 3;
  const int n0a = mw*32 + q*4, n0b = n0a + 16;
  const int sA = nh*32 + cc,   sB = sA + 16;

  #pragma unroll 1
  for (int s = 0; s < 12; ++s) {
    // ---- step prologue: chunk-0 global prefetch (no LDS dep) ----
    int4 br0, br1;
    {
      const unsigned short* src = W2n + (size_t)brow*64 + bpart*16;
      br0 = *(const int4*)src; br1 = *(const int4*)(src + 8);
    }
    f32x2 er = {0.f, 0.f};
    if (tid < 100) er = *(const f32x2*)(ehPg + tid*2);

    // X fragments in registers (chunk-invariant this step): from hf, pk2 (RTNE)
    bf16x8 xf00, xf01, xf10, xf11;
    {
      int xr0 = nh*32 + cc, xr1 = xr0 + 16;
      union { bf16x8 v; uint u[4]; } X;
      #pragma unroll
      for (int half = 0; half < 4; ++half) {
        int row = (half & 1) ? xr1 : xr0;
        int d0  = (half & 2) ? (32 + q*8) : (q*8);
        if (row < 50) {
          const float* p = &hf[row*64 + d0];
          float4 a = *(const float4*)p;
          float4 b = *(const float4*)(p+4);
          X.u[0]=pk2(a.x,a.y); X.u[1]=pk2(a.z,a.w); X.u[2]=pk2(b.x,b.y); X.u[3]=pk2(b.z,b.w);
        } else { X.u[0]=0; X.u[1]=0; X.u[2]=0; X.u[3]=0; }
        if (half==0) xf00=X.v; else if (half==1) xf10=X.v; else if (half==2) xf01=X.v; else xf11=X.v;
      }
    }

    // step-prologue LDS writes: chunk-0 B + eh pair
    *(int4*)(BtB + (brow<<7) + (((bpart*2  )^(brow&7))<<4)) = br0;
    *(int4*)(BtB + (brow<<7) + (((bpart*2+1)^(brow&7))<<4)) = br1;
    if (tid < 100) ehl2[0][tid] = er;
    __syncthreads();

    f32x2 fin01={0,0}, fin23={0,0}, fin45={0,0}, fin67={0,0};

    #pragma unroll 1
    for (int c = 0; c < 64; ++c) {
      // ---- phase A: MFMA T_c from BtB + Tt f32 write + prefetch-issue ----
      f32x4 tc00={}, tc01={}, tc10={}, tc11={};
      {
        int ar0 = mw*32 + cc, ar1 = ar0 + 16;
        #pragma unroll
        for (int ks = 0; ks < 2; ++ks) {
          bf16x8 af0 = *(const bf16x8*)(BtB + (ar0<<7) + (((ks*4+q)^(ar0&7))<<4));
          bf16x8 af1 = *(const bf16x8*)(BtB + (ar1<<7) + (((ks*4+q)^(ar1&7))<<4));
          bf16x8 xb0 = ks ? xf01 : xf00;
          bf16x8 xb1 = ks ? xf11 : xf10;
          tc00 = __builtin_amdgcn_mfma_f32_16x16x32_bf16(af0, xb0, tc00, 0,0,0);
          tc01 = __builtin_amdgcn_mfma_f32_16x16x32_bf16(af0, xb1, tc01, 0,0,0);
          tc10 = __builtin_amdgcn_mfma_f32_16x16x32_bf16(af1, xb0, tc10, 0,0,0);
          tc11 = __builtin_amdgcn_mfma_f32_16x16x32_bf16(af1, xb1, tc11, 0,0,0);
        }
      }
      {
        float4 v;
        v.x=tc00[0]; v.y=tc00[1]; v.z=tc00[2]; v.w=tc00[3];
        *(float4*)&Tt[sA*132 + n0a] = v;
        v.x=tc01[0]; v.y=tc01[1]; v.z=tc01[2]; v.w=tc01[3];
        *(float4*)&Tt[sB*132 + n0a] = v;
        v.x=tc10[0]; v.y=tc10[1]; v.z=tc10[2]; v.w=tc10[3];
        *(float4*)&Tt[sA*132 + n0b] = v;
        v.x=tc11[0]; v.y=tc11[1]; v.z=tc11[2]; v.w=tc11[3];
        *(float4*)&Tt[sB*132 + n0b] = v;
      }
      if (c < 63) {
        const unsigned short* src = W2n + ((size_t)(c+1)*128 + brow)*64 + bpart*16;
        br0 = *(const int4*)src; br1 = *(const int4*)(src + 8);
        if (tid < 100) er = *(const f32x2*)(ehPg + (size_t)(c+1)*N_EDGES*2 + tid*2);
      }
      __syncthreads();   // barrier 1: Tt ready; BtB reads done
      // ---- phase B: gather + next-chunk LDS writes ----
      {
        const f32x2* ebuf = ehl2[c & 1];
        for (int ii = 0; ii < mydg; ++ii) {
          int pk = (ii==0)?se0:(ii==1)?se1:(ii==2)?se2:(ii==3)?se3:sel[myo+ii];
          int s2 = pk & 0xffff, e2 = pk >> 16;
          f32x2 ep = ebuf[e2];
          const float* tb = &Tt[s2*132 + dq*8];
          union { float4 f4; f32x2 h[2]; } a0, a1, b0, b1;
          a0.f4 = *(const float4*)(tb);
          a1.f4 = *(const float4*)(tb + 4);
          b0.f4 = *(const float4*)(tb + 64);
          b1.f4 = *(const float4*)(tb + 68);
          f32x2 ex = {ep.x, ep.x}, ey = {ep.y, ep.y};
          fin01 += a0.h[0]*ex + b0.h[0]*ey;
          fin23 += a0.h[1]*ex + b0.h[1]*ey;
          fin45 += a1.h[0]*ex + b1.h[0]*ey;
          fin67 += a1.h[1]*ex + b1.h[1]*ey;
        }
      }
      if (c < 63) {
        *(int4*)(BtB + (brow<<7) + (((bpart*2  )^(brow&7))<<4)) = br0;
        *(int4*)(BtB + (brow<<7) + (((bpart*2+1)^(brow&7))<<4)) = br1;
        if (tid < 100) ehl2[(c+1)&1][tid] = er;
      }
      __syncthreads();   // barrier 2: gather done before Tt/BtB overwritten
    }

    // ---- epilogue: + Q gather (Ql, LDS), write aggL (overlays Tt) ----
    {
      for (int ii = 0; ii < mydg; ++ii) {
        int pk = (ii==0)?se0:(ii==1)?se1:(ii==2)?se2:(ii==3)?se3:sel[myo+ii];
        int s2 = pk & 0xffff;
        const float* qp = &Ql[s2*64 + dq*8];
        union { float4 f4; f32x2 h[2]; } q0, q1;
        q0.f4 = *(const float4*)(qp);
        q1.f4 = *(const float4*)(qp + 4);
        fin01 += q0.h[0]; fin23 += q0.h[1];
        fin45 += q1.h[0]; fin67 += q1.h[1];
      }
      // final chunk barrier guarantees all gathers done reading Tt
      float4 f0 = {fin01.x, fin01.y, fin23.x, fin23.y};
      float4 f1 = {fin45.x, fin45.y, fin67.x, fin67.y};
      *(float4*)&aggL[r*66 + dq*8]     = f0;
      *(float4*)&aggL[r*66 + dq*8 + 4] = f1;
    }
    __syncthreads();

    // ---- GRU (8 nodes/wave): ot from hf, write hf + Ql ----
    {
      float ot[8];
      #pragma unroll
      for (int i = 0; i < 8; ++i) {
        int n = wave*8 + i;
        ot[i] = (n < 50) ? hf[n*64+t] : 0.f;
      }
      float mm[8];
      {
        float rc[8] = {0,0,0,0,0,0,0,0};
        for (int d = 0; d < 64; ++d) {
          float w = rootw[d*64+t];
          #pragma unroll
          for (int i = 0; i < 8; ++i) rc[i] += rl(ot[i], d) * w;
        }
        float cb = conv_b[t];
        #pragma unroll
        for (int i = 0; i < 8; ++i) {
          int n = wave*8 + i;
          mm[i] = lrelu(aggL[n*66 + t]*invd[n] + rc[i] + cb);
        }
      }
      float air[8]={}, aiz[8]={}, ain[8]={}, ahr[8]={}, ahz[8]={}, ahn[8]={};
      for (int d = 0; d < 64; ++d) {
        const float* wp = gw6 + (size_t)(d*64+t)*8;
        float4 w0 = *(const float4*)wp;
        float4 w1 = *(const float4*)(wp + 4);
        #pragma unroll
        for (int i = 0; i < 8; ++i) {
          float md = rl(mm[i], d), hd = rl(ot[i], d);
          air[i] += md*w0.x; aiz[i] += md*w0.y; ain[i] += md*w0.z;
          ahr[i] += hd*w0.w; ahz[i] += hd*w1.x; ahn[i] += hd*w1.y;
        }
      }
      float bi0 = bih[t], bi1 = bih[64+t], bi2 = bih[128+t];
      float bh0 = bhh[t], bh1 = bhh[64+t], bh2 = bhh[128+t];
      float h[8];
      #pragma unroll
      for (int i = 0; i < 8; ++i) {
        int n = wave*8 + i;
        float rg = sigm(air[i] + bi0 + ahr[i] + bh0);
        float zg = sigm(aiz[i] + bi1 + ahz[i] + bh1);
        float ng = tanhf(ain[i] + bi2 + rg*(ahn[i] + bh2));
        h[i] = (1.f - zg)*ng + zg*ot[i];
        if (n < 50) hf[n*64+t] = h[i];
      }
      float qa[8] = {0,0,0,0,0,0,0,0};
      for (int d = 0; d < 64; ++d) {
        float qw = net2_b[d*64+t];
        #pragma unroll
        for (int i = 0; i < 8; ++i) qa[i] += rl(h[i], d) * qw;
      }
      #pragma unroll
      for (int i = 0; i < 8; ++i) {
        int n = wave*8 + i;
        if (n < 50) Ql[n*64+t] = qa[i];
      }
    }
    __syncthreads();   // hf/Ql stable for next step; aggL(Tt) free for reuse
  }

  // ---- writeback ----
  for (int i = tid; i < 3200; i += 512) outf[(size_t)g*3200 + i] = hf[i];
}

// ---------------- per-stem head ----------------
__global__ __launch_bounds__(256) void k_stem(const float* __restrict__ outf,
    const int* __restrict__ stems, const int* __restrict__ stems_batch,
    const float* __restrict__ l1T, const float* __restrict__ l1b,
    const float* __restrict__ l2T, const float* __restrict__ l2b,
    float* __restrict__ per_stem) {
  int t = threadIdx.x & 63;
  int s = blockIdx.x*4 + (threadIdx.x>>6);
  int node = stems_batch[s]*50 + stems[s];
  float sx = outf[node*64+t];
  float t1[8];
  #pragma unroll
  for (int g = 0; g < 8; ++g) t1[g] = l1b[g*64+t];
  for (int d = 0; d < 64; ++d) {
    float xd = __shfl(sx, d);
    const float* L = l1T + d*512 + t;
    #pragma unroll
    for (int g = 0; g < 8; ++g) t1[g] += xd * L[g*64];
  }
  #pragma unroll
  for (int g = 0; g < 8; ++g) t1[g] = lrelu(t1[g]);
  float a0 = l2b[t];
  float a1 = (t < 41) ? l2b[64+t] : 0.f;
  for (int g = 0; g < 8; ++g) {
    for (int d = 0; d < 64; ++d) {
      float tj = __shfl(t1[g], d);
      int j = g*64 + d;
      a0 += tj * l2T[j*105 + t];
      a1 += tj * ((t < 41) ? l2T[j*105 + 64 + t] : 0.f);
    }
  }
  per_stem[s*105 + t] = a0;
  if (t < 41) per_stem[s*105 + 64 + t] = a1;
}

// ---------------- Set2Set (3 LSTM-attention steps) + final linear ----------------
__global__ __launch_bounds__(64) void k_s2s(const float* __restrict__ outf,
    const float* __restrict__ wihT, const float* __restrict__ whhT,
    const float* __restrict__ bih, const float* __restrict__ bhh,
    const float* __restrict__ l3w, const float* __restrict__ l3b,
    float* __restrict__ sout) {
  int b = blockIdx.x, t = threadIdx.x;
  const float* og = outf + b*50*64;
  float qlo = 0.f, qhi = 0.f, hs = 0.f, cs = 0.f;
  float b0 = bih[t]+bhh[t], b1 = bih[64+t]+bhh[64+t], b2 = bih[128+t]+bhh[128+t], b3 = bih[192+t]+bhh[192+t];
  for (int it = 0; it < 3; ++it) {
    float g0 = b0, g1 = b1, g2 = b2, g3 = b3;
    for (int c = 0; c < 64; ++c) {
      float qc = __shfl(qlo, c);
      const float* L = wihT + c*256 + t;
      g0 += qc*L[0]; g1 += qc*L[64]; g2 += qc*L[128]; g3 += qc*L[192];
    }
    for (int c = 0; c < 64; ++c) {
      float qc = __shfl(qhi, c);
      const float* L = wihT + (64+c)*256 + t;
      g0 += qc*L[0]; g1 += qc*L[64]; g2 += qc*L[128]; g3 += qc*L[192];
    }
    for (int d = 0; d < 64; ++d) {
      float hd = __shfl(hs, d);
      const float* L = whhT + d*256 + t;
      g0 += hd*L[0]; g1 += hd*L[64]; g2 += hd*L[128]; g3 += hd*L[192];
    }
    float ig = sigm(g0), fg = sigm(g1), cg = tanhf(g2), oo = sigm(g3);
    cs = fg*cs + ig*cg;
    hs = oo*tanhf(cs);
    float ei = -3.4e38f;
    for (int i = 0; i < 50; ++i) {
      float p = og[i*64+t]*hs;
      #pragma unroll
      for (int m2 = 1; m2 < 64; m2 <<= 1) p += __shfl_xor(p, m2);
      if (t == i) ei = p;
    }
    float em = ei;
    #pragma unroll
    for (int m2 = 1; m2 < 64; m2 <<= 1) em = fmaxf(em, __shfl_xor(em, m2));
    float av = (t < 50) ? __expf(ei - em) : 0.f;
    float as = av;
    #pragma unroll
    for (int m2 = 1; m2 < 64; m2 <<= 1) as += __shfl_xor(as, m2);
    av /= as;
    float rr = 0.f;
    for (int i = 0; i < 50; ++i) rr += __shfl(av, i) * og[i*64+t];
    qlo = hs; qhi = rr;
  }
  float p = qlo*l3w[t] + qhi*l3w[64+t];
  #pragma unroll
  for (int m2 = 1; m2 < 64; m2 <<= 1) p += __shfl_xor(p, m2);
  if (t == 0) sout[b] = p + l3b[0];
}

extern "C" void kernel_launch(void* const* d_in, const int* in_sizes, int n_in,
                              void* d_out, int out_size, void* d_ws, size_t ws_size,
                              hipStream_t stream) {
  const float* x          = (const float*)d_in[0];
  const float* edge_attr  = (const float*)d_in[1];
  const int*   edge_index = (const int*)  d_in[2];
  const int*   stems      = (const int*)  d_in[4];
  const int*   stems_b    = (const int*)  d_in[5];
  const float* lin0_w = (const float*)d_in[6];
  const float* lin0_b = (const float*)d_in[7];
  const float* net1_w = (const float*)d_in[8];
  const float* net1_b = (const float*)d_in[9];
  const float* net2_w = (const float*)d_in[10];
  const float* net2_b = (const float*)d_in[11];
  const float* root_w = (const float*)d_in[12];
  const float* conv_b = (const float*)d_in[13];
  const float* gru_wih = (const float*)d_in[14];
  const float* gru_whh = (const float*)d_in[15];
  const float* gru_bih = (const float*)d_in[16];
  const float* gru_bhh = (const float*)d_in[17];
  const float* lin1_w = (const float*)d_in[18];
  const float* lin1_b = (const float*)d_in[19];
  const float* lin2_w = (const float*)d_in[20];
  const float* lin2_b = (const float*)d_in[21];
  const float* lstm_wih = (const float*)d_in[22];
  const float* lstm_whh = (const float*)d_in[23];
  const float* lstm_bih = (const float*)d_in[24];
  const float* lstm_bhh = (const float*)d_in[25];
  const float* lin3_w = (const float*)d_in[26];
  const float* lin3_b = (const float*)d_in[27];

  char* ws = (char*)d_ws;
  size_t off = 0;
  auto alloc = [&](size_t bytes) { void* p = ws + off; off += (bytes + 255) & ~(size_t)255; return p; };
  float* ehP  = (float*)alloc((size_t)N_EDGES*128*4);          // 26.2MB  [c][e][2]
  unsigned short* W2n = (unsigned short*)alloc(524288*2);      // 1MB
  float* outf = (float*)alloc((size_t)N_NODES*64*4);
  int* deg  = (int*)alloc(N_NODES*4);
  int* offs = (int*)alloc(N_NODES*4);
  int* csr  = (int*)alloc(N_EDGES*4);
  float* gw6   = (float*)alloc(32768*4);
  float* lwihT = (float*)alloc(32768*4);
  float* lwhhT = (float*)alloc(16384*4);
  float* l1T   = (float*)alloc(32768*4);
  float* l2T   = (float*)alloc(53760*4);
  float* l0T   = (float*)alloc(1536*4);

  if (off > ws_size) {   // diagnosable fallback (signature absmax 1.5625e-1)
    hipMemsetAsync(d_out, 0, (size_t)out_size * sizeof(float), stream);
    return;
  }

  float* per_stem = (float*)d_out;
  float* sout = per_stem + 2560*105;

  k_prep<<<2712, 256, 0, stream>>>(net2_w, W2n, gru_wih, gru_whh, gw6,
                                   lstm_wih, lstm_whh, lwihT, lwhhT,
                                   lin1_w, l1T, lin2_w, l2T, lin0_w, l0T);
  k_lin0<<<N_NODES/4, 256, 0, stream>>>(x, l0T, lin0_b, outf);
  k_eh<<<N_EDGES/64, 256, 0, stream>>>(edge_attr, net1_w, net1_b, ehP);
  k_csr<<<NG, 128, 0, stream>>>(edge_index, deg, offs, csr);
  k_conv<<<NG, 512, 0, stream>>>(outf, ehP, W2n, edge_index, csr, offs, deg,
                                 root_w, conv_b, gw6, gru_bih, gru_bhh, net2_b);
  k_stem<<<2560/4, 256, 0, stream>>>(outf, stems, stems_b, l1T, lin1_b, l2T, lin2_b, per_stem);
  k_s2s<<<NG, 64, 0, stream>>>(outf, lwihT, lwhhT, lstm_bih, lstm_bhh, lin3_w, lin3_b, sout);
}